// Round 2
// baseline (4672.996 us; speedup 1.0000x reference)
//
#include <hip/hip_runtime.h>

// T=1024, B=256, I=256, H=256, fp32 in/out.
// out = outputs [T,B,H] flat, then final state [B,H].
//
// FUSED single kernel: 64 blocks x 256 threads, 1 block/CU on 64 CUs.
// Both W_hh and W_xh persistent in f16 B-fragments (~256 VGPR; launch_bounds
// (256,1) gives the 512-VGPR budget; we're at 1 block/CU anyway).
// Per step t:
//   - ds_read state frags (double-buffered LDS, pad 272 -> conflict-free)
//   - issue X[t+2] loads (X is __restrict__ != out -> no false alias ordering
//     against the h stores; loads fly across the barrier, vmcnt counted)
//   - recurrence MFMA (E/O split, depth 4) + tanh -> store h + ds_write state
//   - xw[t+2] = X[t+2]@W_xh + b via independent MFMA chain (result consumed
//     2 steps later -> pure slack-filler for the matrix pipe at 8% util)
//   - lgkmcnt(0) + raw s_barrier (vmcnt NEVER drained)
// This deletes the 520us xw_gemm pre-pass and out's 132MB of xw re-reads.

#define TT 1024
#define BB 256
#define HH 256

typedef __attribute__((ext_vector_type(8))) _Float16 f16x8;
typedef __attribute__((ext_vector_type(4))) float f32x4;

__device__ __forceinline__ float fast_tanh(float x) {
    float e = __expf(2.0f * x);
    return 1.0f - 2.0f * __builtin_amdgcn_rcpf(e + 1.0f);
}

#define SP 272  // state row pad: reads 2-way (free), writes conflict-free

#define PACK8(DST, LO, HI)                                                        \
    {                                                                             \
        f16x8 v_;                                                                 \
        v_[0] = (_Float16)(LO).x; v_[1] = (_Float16)(LO).y;                       \
        v_[2] = (_Float16)(LO).z; v_[3] = (_Float16)(LO).w;                       \
        v_[4] = (_Float16)(HI).x; v_[5] = (_Float16)(HI).y;                       \
        v_[6] = (_Float16)(HI).z; v_[7] = (_Float16)(HI).w;                       \
        DST = v_;                                                                 \
    }

// xw = X[TP] @ W_xh + b for this lane's 4 output elements (prologue use)
#define XWINIT(TP, DST)                                                           \
    {                                                                             \
        f16x8 axf[8];                                                             \
        if (realrow) {                                                            \
            const float* xp = X + ((size_t)(TP)*BB + b0 + r) * HH + quad * 8;     \
            _Pragma("unroll")                                                     \
            for (int kt = 0; kt < 8; kt++) {                                      \
                float4 lo = *(const float4*)(xp + kt * 32);                       \
                float4 hi = *(const float4*)(xp + kt * 32 + 4);                   \
                PACK8(axf[kt], lo, hi)                                            \
            }                                                                     \
        } else {                                                                  \
            _Pragma("unroll")                                                     \
            for (int kt = 0; kt < 8; kt++) axf[kt] = (f16x8)(_Float16)0.f;        \
        }                                                                         \
        f32x4 accX[4];                                                            \
        _Pragma("unroll")                                                         \
        for (int nt = 0; nt < 4; nt++) accX[nt] = (f32x4){bbx[nt], 0.f, 0.f, 0.f};\
        _Pragma("unroll")                                                         \
        for (int kt = 0; kt < 8; kt++)                                            \
            _Pragma("unroll")                                                     \
            for (int nt = 0; nt < 4; nt++)                                        \
                accX[nt] = __builtin_amdgcn_mfma_f32_16x16x32_f16(axf[kt], bfx[nt][kt], accX[nt], 0, 0, 0); \
        _Pragma("unroll")                                                         \
        for (int nt = 0; nt < 4; nt++) DST[nt] = accX[nt][0];                     \
    }

// One recurrence step. CUR/NXT compile-time 0/1. XW holds xw[T] on entry and
// is refilled with xw[T+2] on exit (consumed 2 steps later).
#define STEP(T, XW, CUR, NXT)                                                     \
    {                                                                             \
        f16x8 af[8];                                                              \
        if (realrow) {                                                            \
            _Pragma("unroll")                                                     \
            for (int kt = 0; kt < 8; kt++)                                        \
                af[kt] = *(const f16x8*)&st[CUR][r][kt * 32 + quad * 8];          \
        } else {                                                                  \
            _Pragma("unroll")                                                     \
            for (int kt = 0; kt < 8; kt++) af[kt] = (f16x8)(_Float16)0.f;         \
        }                                                                         \
        /* X[t+2] loads: distinct restrict pointer, no ordering vs out stores */  \
        f16x8 axf[8];                                                             \
        {                                                                         \
            const int tp = ((T) + 2 > TT - 1) ? (TT - 1) : ((T) + 2);             \
            if (realrow) {                                                        \
                const float* xp = X + ((size_t)tp * BB + b0 + r) * HH + quad * 8; \
                _Pragma("unroll")                                                 \
                for (int kt = 0; kt < 8; kt++) {                                  \
                    float4 lo = *(const float4*)(xp + kt * 32);                   \
                    float4 hi = *(const float4*)(xp + kt * 32 + 4);               \
                    PACK8(axf[kt], lo, hi)                                        \
                }                                                                 \
            } else {                                                              \
                _Pragma("unroll")                                                 \
                for (int kt = 0; kt < 8; kt++) axf[kt] = (f16x8)(_Float16)0.f;    \
            }                                                                     \
        }                                                                         \
        /* recurrence: E/O split -> two 4-deep MFMA chains per nt */              \
        f32x4 accE[4], accO[4];                                                   \
        _Pragma("unroll")                                                         \
        for (int nt = 0; nt < 4; nt++) {                                          \
            accE[nt] = (f32x4){XW[nt], 0.f, 0.f, 0.f};                            \
            accO[nt] = (f32x4){0.f, 0.f, 0.f, 0.f};                               \
        }                                                                         \
        _Pragma("unroll")                                                         \
        for (int kt = 0; kt < 4; kt++)                                            \
            _Pragma("unroll")                                                     \
            for (int nt = 0; nt < 4; nt++) {                                      \
                accE[nt] = __builtin_amdgcn_mfma_f32_16x16x32_f16(af[2 * kt],     bf[nt][2 * kt],     accE[nt], 0, 0, 0); \
                accO[nt] = __builtin_amdgcn_mfma_f32_16x16x32_f16(af[2 * kt + 1], bf[nt][2 * kt + 1], accO[nt], 0, 0, 0); \
            }                                                                     \
        const size_t obase = (size_t)(T) * (BB * HH) + colbase;                   \
        _Pragma("unroll")                                                         \
        for (int nt = 0; nt < 4; nt++) {                                          \
            h[nt] = fast_tanh(accE[nt][0] + accO[nt][0]);                         \
            out[obase + nt * 16] = h[nt];                                         \
            st[NXT][quad][wave * 64 + nt * 16 + c] = (_Float16)h[nt];             \
        }                                                                         \
        /* xw[t+2]: independent chain, fills matrix-pipe slack */                 \
        f32x4 accX[4];                                                            \
        _Pragma("unroll")                                                         \
        for (int nt = 0; nt < 4; nt++) accX[nt] = (f32x4){bbx[nt], 0.f, 0.f, 0.f};\
        _Pragma("unroll")                                                         \
        for (int kt = 0; kt < 8; kt++)                                            \
            _Pragma("unroll")                                                     \
            for (int nt = 0; nt < 4; nt++)                                        \
                accX[nt] = __builtin_amdgcn_mfma_f32_16x16x32_f16(axf[kt], bfx[nt][kt], accX[nt], 0, 0, 0); \
        _Pragma("unroll")                                                         \
        for (int nt = 0; nt < 4; nt++) XW[nt] = accX[nt][0];                      \
        /* ds ops retired, then barrier; vmcnt NOT drained */                     \
        asm volatile("s_waitcnt lgkmcnt(0)" ::: "memory");                        \
        __builtin_amdgcn_s_barrier();                                             \
        __builtin_amdgcn_sched_barrier(0);                                        \
    }

__global__ __launch_bounds__(256, 1) void rnn_fused(const float* __restrict__ X,
                                                    const float* __restrict__ Wxh,
                                                    const float* __restrict__ Whh,
                                                    const float* __restrict__ bh,
                                                    float* __restrict__ out) {
    // double-buffered state: step t reads st[t&1], writes st[(t+1)&1]
    __shared__ alignas(16) _Float16 st[2][4][SP];

    const int tid  = threadIdx.x;
    const int lane = tid & 63;
    const int wave = tid >> 6;        // N slice [wave*64, wave*64+64)
    const int c    = lane & 15;
    const int quad = lane >> 4;
    const int b0   = blockIdx.x * 4;  // batch rows b0..b0+3 at m = 4*r

    // persistent B fragments for BOTH weight matrices:
    // bf [nt][kt][j] = W_hh[kt*32+quad*8+j][wave*64+nt*16+c]
    // bfx[nt][kt][j] = W_xh[kt*32+quad*8+j][wave*64+nt*16+c]
    f16x8 bf[4][8], bfx[4][8];
#pragma unroll
    for (int nt = 0; nt < 4; nt++) {
        const int n = wave * 64 + nt * 16 + c;
#pragma unroll
        for (int kt = 0; kt < 8; kt++) {
            const int kb = kt * 32 + quad * 8;
            f16x8 v, w;
#pragma unroll
            for (int j = 0; j < 8; j++) {
                v[j] = (_Float16)Whh[(size_t)(kb + j) * HH + n];
                w[j] = (_Float16)Wxh[(size_t)(kb + j) * HH + n];
            }
            bf[nt][kt]  = v;
            bfx[nt][kt] = w;
        }
    }
    float bbx[4];
#pragma unroll
    for (int nt = 0; nt < 4; nt++) bbx[nt] = bh[wave * 64 + nt * 16 + c];

    // zero both state buffers
    for (int i = tid; i < 2 * 4 * SP; i += 256)
        ((_Float16*)st)[i] = (_Float16)0.f;

    const int  m       = c;               // A-row this lane serves
    const bool realrow = ((m & 3) == 0);
    const int  r       = m >> 2;          // batch row for real A lanes

    const size_t colbase = (size_t)(b0 + quad) * HH + wave * 64 + c;

    // prologue: xw for t=0 and t=1
    float xwA[4], xwB[4];
    XWINIT(0, xwA)
    XWINIT(1, xwB)

    asm volatile("s_waitcnt lgkmcnt(0)" ::: "memory");
    __builtin_amdgcn_s_barrier();
    __builtin_amdgcn_sched_barrier(0);

    float h[4] = {0.f, 0.f, 0.f, 0.f};

#pragma unroll 1
    for (int t = 0; t < TT; t += 2) {
        STEP(t,     xwA, 0, 1)
        STEP(t + 1, xwB, 1, 0)
    }

    const size_t fbase = (size_t)TT * (BB * HH) + colbase;
#pragma unroll
    for (int nt = 0; nt < 4; nt++) out[fbase + nt * 16] = h[nt];
}

extern "C" void kernel_launch(void* const* d_in, const int* in_sizes, int n_in,
                              void* d_out, int out_size, void* d_ws, size_t ws_size,
                              hipStream_t stream) {
    const float* X   = (const float*)d_in[0];  // [T,B,I]
    const float* Wxh = (const float*)d_in[1];  // [I,H]
    const float* Whh = (const float*)d_in[2];  // [H,H]
    const float* bh  = (const float*)d_in[3];  // [H]
    float* out = (float*)d_out;

    rnn_fused<<<dim3(BB / 4), dim3(256), 0, stream>>>(X, Wxh, Whh, bh, out);
}

// Round 3
// 1131.767 us; speedup vs baseline: 4.1289x; 4.1289x over previous
//
#include <hip/hip_runtime.h>

// T=1024, B=256, I=256, H=256, fp32 in/out.
// out = outputs [T,B,H] flat, then final state [B,H].
//
// Two kernels again (round-2 fusion hit the 256-VGPR arch cap -> scratch
// spill of weights, 7x regression). The round-2 insight that survives:
// kernel B must NOT load xw from `out` (may-alias with its own h stores ->
// compiler emits s_waitcnt vmcnt(0) = full store drain every step, ~1000
// wasted cyc/step). Fix: stage xw in d_ws as f16 (separate __restrict__).
//
// Kernel A: f16 MFMA, 16x128 tiles, bfx[2][8]=64 VGPR -> <=128 VGPR ->
//   2 blocks/CU (round-1 A was 1 wave/SIMD, latency-exposed, 520us).
//   Writes ws in a permuted layout: ws[t][b][p], p(n) = (n>>6)*64+(n&15)*4
//   +((n>>4)&3), so B's 4 xw values per lane are one 8B f16x4 load.
// Kernel B: as round-1 but xw from ws (alias-free -> counted vmcnt, stores
//   stay in flight), branchless ds_reads, f16 xw converted at use.
// Fallback if ws_size < 134MB: round-1 behavior (xw fp32 via out).

#define TT 1024
#define BB 256
#define HH 256

typedef __attribute__((ext_vector_type(8))) _Float16 f16x8;
typedef __attribute__((ext_vector_type(4))) _Float16 f16x4;
typedef __attribute__((ext_vector_type(2))) _Float16 f16x2;
typedef __attribute__((ext_vector_type(4))) float f32x4;

__device__ __forceinline__ float fast_tanh(float x) {
    float e = __expf(2.0f * x);
    return 1.0f - 2.0f * __builtin_amdgcn_rcpf(e + 1.0f);
}

// ---------------- Kernel A: xw = X @ W_xh + b ----------------
// grid (2048, 2): y = column half (128 cols), x grid-strides 16-row tiles.
// wave handles 32 cols (2 nt tiles); all 16 rows real -> full MFMA tiles.
template <bool TOWS>
__global__ __launch_bounds__(256, 2) void xw_gemm(const float* __restrict__ X,
                                                  const float* __restrict__ W,
                                                  const float* __restrict__ bh,
                                                  _Float16* __restrict__ ws,
                                                  float* __restrict__ out) {
    const int tid  = threadIdx.x;
    const int lane = tid & 63;
    const int wave = tid >> 6;
    const int c    = lane & 15;
    const int quad = lane >> 4;
    const int hf   = blockIdx.y;
    const int nb   = hf * 128 + wave * 32;  // this wave's first col

    // B frags: bfx[nt][kt][j] = W[kt*32+quad*8+j][nb+nt*16+c]  (64 VGPR)
    f16x8 bfx[2][8];
#pragma unroll
    for (int nt = 0; nt < 2; nt++) {
        const int n = nb + nt * 16 + c;
#pragma unroll
        for (int kt = 0; kt < 8; kt++) {
            const int kb = kt * 32 + quad * 8;
            f16x8 v;
#pragma unroll
            for (int j = 0; j < 8; j++)
                v[j] = (_Float16)W[(size_t)(kb + j) * HH + n];
            bfx[nt][kt] = v;
        }
    }
    float bb[2];
#pragma unroll
    for (int nt = 0; nt < 2; nt++) bb[nt] = bh[nb + nt * 16 + c];

    const int ntiles = (TT * BB) / 16;
    for (int rt = blockIdx.x; rt < ntiles; rt += gridDim.x) {
        const float* xp = X + ((size_t)rt * 16 + c) * HH + quad * 8;
        f16x8 af[8];
#pragma unroll
        for (int kt = 0; kt < 8; kt++) {
            float4 lo = *(const float4*)(xp + kt * 32);
            float4 hi = *(const float4*)(xp + kt * 32 + 4);
            f16x8 v;
            v[0] = (_Float16)lo.x; v[1] = (_Float16)lo.y;
            v[2] = (_Float16)lo.z; v[3] = (_Float16)lo.w;
            v[4] = (_Float16)hi.x; v[5] = (_Float16)hi.y;
            v[6] = (_Float16)hi.z; v[7] = (_Float16)hi.w;
            af[kt] = v;
        }

        f32x4 acc[2];
#pragma unroll
        for (int nt = 0; nt < 2; nt++) acc[nt] = (f32x4){0.f, 0.f, 0.f, 0.f};
#pragma unroll
        for (int kt = 0; kt < 8; kt++)
#pragma unroll
            for (int nt = 0; nt < 2; nt++)
                acc[nt] = __builtin_amdgcn_mfma_f32_16x16x32_f16(af[kt], bfx[nt][kt], acc[nt], 0, 0, 0);

        if (TOWS) {
            // permuted f16 store: cols n, n+16 land at adjacent p -> f16x2
            const int pbase = (hf * 2 + (wave >> 1)) * 64 + c * 4 + (wave & 1) * 2;
#pragma unroll
            for (int i = 0; i < 4; i++) {
                const size_t R = (size_t)rt * 16 + quad * 4 + i;
                f16x2 v;
                v[0] = (_Float16)(acc[0][i] + bb[0]);
                v[1] = (_Float16)(acc[1][i] + bb[1]);
                *(f16x2*)(ws + R * HH + pbase) = v;
            }
        } else {
#pragma unroll
            for (int i = 0; i < 4; i++) {
                const size_t R = (size_t)rt * 16 + quad * 4 + i;
#pragma unroll
                for (int nt = 0; nt < 2; nt++)
                    out[R * HH + nb + nt * 16 + c] = acc[nt][i] + bb[nt];
            }
        }
    }
}

// ---------------- Kernel B: MFMA recurrence ----------------
#define SP 272  // state row pad: reads 2-way (free), writes conflict-free

// One step. CUR/NXT compile-time 0/1. XWH (ws path, f16x4) or XWF (fallback,
// float[4]) holds xw[T] on entry, refilled with xw[T+2] (consumed 2 steps on).
#define STEP(T, XWH, XWF, CUR, NXT)                                               \
    {                                                                             \
        f16x8 af[8]; /* branchless: fake rows read row r (harmless) */            \
        _Pragma("unroll")                                                         \
        for (int kt = 0; kt < 8; kt++)                                            \
            af[kt] = *(const f16x8*)&st[CUR][r][kt * 32 + quad * 8];              \
        f32x4 accE[4], accO[4];                                                   \
        _Pragma("unroll")                                                         \
        for (int nt = 0; nt < 4; nt++) {                                          \
            float xv;                                                             \
            if constexpr (FROMWS) xv = (float)XWH[nt]; else xv = XWF[nt];         \
            accE[nt] = (f32x4){xv, 0.f, 0.f, 0.f};                                \
            accO[nt] = (f32x4){0.f, 0.f, 0.f, 0.f};                               \
        }                                                                         \
        /* prefetch xw[T+2]: alias-free vs out stores -> counted vmcnt */         \
        {                                                                         \
            const int tp = ((T) + 2 > TT - 1) ? (TT - 1) : ((T) + 2);             \
            if constexpr (FROMWS) {                                               \
                XWH = *(const f16x4*)(ws + (size_t)tp * (BB * HH) + wsoff);       \
            } else {                                                              \
                _Pragma("unroll")                                                 \
                for (int nt = 0; nt < 4; nt++)                                    \
                    XWF[nt] = out[(size_t)tp * (BB * HH) + colbase + nt * 16];    \
            }                                                                     \
        }                                                                         \
        _Pragma("unroll")                                                         \
        for (int kt = 0; kt < 4; kt++)                                            \
            _Pragma("unroll")                                                     \
            for (int nt = 0; nt < 4; nt++) {                                      \
                accE[nt] = __builtin_amdgcn_mfma_f32_16x16x32_f16(af[2 * kt],     bf[nt][2 * kt],     accE[nt], 0, 0, 0); \
                accO[nt] = __builtin_amdgcn_mfma_f32_16x16x32_f16(af[2 * kt + 1], bf[nt][2 * kt + 1], accO[nt], 0, 0, 0); \
            }                                                                     \
        const size_t obase = (size_t)(T) * (BB * HH) + colbase;                   \
        _Pragma("unroll")                                                         \
        for (int nt = 0; nt < 4; nt++) {                                          \
            h[nt] = fast_tanh(accE[nt][0] + accO[nt][0]);                         \
            out[obase + nt * 16] = h[nt];                                         \
            st[NXT][quad][wave * 64 + nt * 16 + c] = (_Float16)h[nt];             \
        }                                                                         \
        asm volatile("s_waitcnt lgkmcnt(0)" ::: "memory");                        \
        __builtin_amdgcn_s_barrier();                                             \
        __builtin_amdgcn_sched_barrier(0);                                        \
    }

template <bool FROMWS>
__global__ __launch_bounds__(256, 1) void rnn_rec_mfma(const float* __restrict__ Whh,
                                                       const _Float16* __restrict__ ws,
                                                       float* __restrict__ out) {
    __shared__ alignas(16) _Float16 st[2][4][SP];

    const int tid  = threadIdx.x;
    const int lane = tid & 63;
    const int wave = tid >> 6;        // N slice [wave*64, wave*64+64)
    const int c    = lane & 15;
    const int quad = lane >> 4;
    const int b0   = blockIdx.x * 4;  // batch rows b0..b0+3 at m = 4*r

    f16x8 bf[4][8];
#pragma unroll
    for (int nt = 0; nt < 4; nt++) {
        const int n = wave * 64 + nt * 16 + c;
#pragma unroll
        for (int kt = 0; kt < 8; kt++) {
            const int kb = kt * 32 + quad * 8;
            f16x8 v;
#pragma unroll
            for (int j = 0; j < 8; j++)
                v[j] = (_Float16)Whh[(size_t)(kb + j) * HH + n];
            bf[nt][kt] = v;
        }
    }

    for (int i = tid; i < 2 * 4 * SP; i += 256)
        ((_Float16*)st)[i] = (_Float16)0.f;

    const int r = c >> 2;  // state row (valid for all lanes; fake rows benign)

    const size_t colbase = (size_t)(b0 + quad) * HH + wave * 64 + c;       // natural
    const size_t wsoff   = (size_t)(b0 + quad) * HH + wave * 64 + c * 4;   // permuted

    f16x4 xwhA, xwhB;
    float xwfA[4], xwfB[4];
    if constexpr (FROMWS) {
        xwhA = *(const f16x4*)(ws + wsoff);                       // t=0
        xwhB = *(const f16x4*)(ws + (size_t)BB * HH + wsoff);     // t=1
    } else {
#pragma unroll
        for (int nt = 0; nt < 4; nt++) xwfA[nt] = out[colbase + nt * 16];
#pragma unroll
        for (int nt = 0; nt < 4; nt++) xwfB[nt] = out[(size_t)BB * HH + colbase + nt * 16];
    }

    asm volatile("s_waitcnt lgkmcnt(0)" ::: "memory");
    __builtin_amdgcn_s_barrier();
    __builtin_amdgcn_sched_barrier(0);

    float h[4] = {0.f, 0.f, 0.f, 0.f};

#pragma unroll 1
    for (int t = 0; t < TT; t += 2) {
        STEP(t,     xwhA, xwfA, 0, 1)
        STEP(t + 1, xwhB, xwfB, 1, 0)
    }

    const size_t fbase = (size_t)TT * (BB * HH) + colbase;
#pragma unroll
    for (int nt = 0; nt < 4; nt++) out[fbase + nt * 16] = h[nt];
}

extern "C" void kernel_launch(void* const* d_in, const int* in_sizes, int n_in,
                              void* d_out, int out_size, void* d_ws, size_t ws_size,
                              hipStream_t stream) {
    const float* X   = (const float*)d_in[0];  // [T,B,I]
    const float* Wxh = (const float*)d_in[1];  // [I,H]
    const float* Whh = (const float*)d_in[2];  // [H,H]
    const float* bh  = (const float*)d_in[3];  // [H]
    float* out = (float*)d_out;

    const size_t need = (size_t)TT * BB * HH * sizeof(_Float16);
    if (d_ws != nullptr && ws_size >= need) {
        _Float16* ws = (_Float16*)d_ws;
        xw_gemm<true><<<dim3(2048, 2), dim3(256), 0, stream>>>(X, Wxh, bh, ws, out);
        rnn_rec_mfma<true><<<dim3(BB / 4), dim3(256), 0, stream>>>(Whh, ws, out);
    } else {
        xw_gemm<false><<<dim3(2048, 2), dim3(256), 0, stream>>>(X, Wxh, bh, nullptr, out);
        rnn_rec_mfma<false><<<dim3(BB / 4), dim3(256), 0, stream>>>(Whh, nullptr, out);
    }
}